// Round 14
// baseline (201.539 us; speedup 1.0000x reference)
//
#include <hip/hip_runtime.h>

#define L     1001
#define H     256
#define B_DIM 32
#define KSHOT 50

typedef float  f32x4   __attribute__((ext_vector_type(4)));
typedef short  short8  __attribute__((ext_vector_type(8)));
typedef unsigned short ushort8 __attribute__((ext_vector_type(8)));
typedef unsigned short ushort4v __attribute__((ext_vector_type(4)));
typedef float  float4a __attribute__((ext_vector_type(4), aligned(4)));
typedef unsigned short ushort_t;

__device__ __forceinline__ unsigned short f2bf(float x) {
  unsigned int u = __float_as_uint(x);
  u += 0x7FFFu + ((u >> 16) & 1u);           // RNE
  return (unsigned short)(u >> 16);
}
__device__ __forceinline__ float bf2f(unsigned short h) {
  return __uint_as_float(((unsigned int)h) << 16);
}

__device__ __forceinline__ void async_copy16(const void* g, void* l) {
  __builtin_amdgcn_global_load_lds(
      (const __attribute__((address_space(1))) void*)g,
      (__attribute__((address_space(3))) void*)l, 16, 0, 0);
}

// ------------------------------------------------- merged prep: qe | vt | kb+qb in one launch
#define QE_BLKS 8008
#define VT_BLKS 2048
#define KQ_BLKS 8192

__global__ __launch_bounds__(256) void prep_kernel(const float* __restrict__ q,
                                                   const float* __restrict__ k,
                                                   const float* __restrict__ v,
                                                   const float* __restrict__ emb,
                                                   float* __restrict__ qe,
                                                   ushort_t* __restrict__ vt,
                                                   ushort_t* __restrict__ kb,
                                                   ushort_t* __restrict__ qb) {
  const int blk = blockIdx.x;
  const int t = threadIdx.x;
  __shared__ ushort_t tile[64][68];

  if (blk < QE_BLKS) {
    const int wid  = (blk << 2) + (t >> 6);
    const int lane = t & 63;
    if (wid >= B_DIM * L) return;
    const float4a qv = *(const float4a*)(q + (size_t)wid * H + lane * 4);
    float acc[6];
#pragma unroll
    for (int c = 0; c < 6; ++c) {
      float4a ev = *(const float4a*)(emb + c * H + lane * 4);
      acc[c] = qv.x * ev.x + qv.y * ev.y + qv.z * ev.z + qv.w * ev.w;
    }
#pragma unroll
    for (int c = 0; c < 6; ++c)
#pragma unroll
      for (int o = 32; o; o >>= 1) acc[c] += __shfl_xor(acc[c], o, 64);
    if (lane == 0) {
      float* dst = qe + (size_t)wid * 6;
      dst[0] = acc[0]; dst[1] = acc[1]; dst[2] = acc[2];
      dst[3] = acc[3]; dst[4] = acc[4]; dst[5] = acc[5];
    }
  } else if (blk < QE_BLKS + VT_BLKS) {
    const int idx = blk - QE_BLKS;
    const int jt = idx & 15, ht = (idx >> 4) & 3, b = idx >> 6;
    const int j0 = jt * 64, h0 = ht * 64;
#pragma unroll
    for (int it = 0; it < 4; ++it) {
      int j = (t >> 4) + it * 16;
      int h = (t & 15) * 4;
      int gj = j0 + j;
      float4a val = {0.f, 0.f, 0.f, 0.f};
      if (gj < L) val = *(const float4a*)(v + ((size_t)b * L + gj) * H + h0 + h);
      tile[j][h + 0] = f2bf(val.x);
      tile[j][h + 1] = f2bf(val.y);
      tile[j][h + 2] = f2bf(val.z);
      tile[j][h + 3] = f2bf(val.w);
    }
    __syncthreads();
#pragma unroll
    for (int it = 0; it < 2; ++it) {
      int h = (t >> 3) + it * 32;
      int j = (t & 7) * 8;
      ushort8 val;
#pragma unroll
      for (int e = 0; e < 8; ++e) val[e] = tile[j + e][h];
      const int hg = h0 + h, jg = j0 + j;
      const int gran = (b * 16 + (hg >> 4)) * 32 + (jg >> 5);
      const int slot = (hg & 15) | (((jg >> 3) & 3) << 4);
      *(ushort8*)(vt + (size_t)gran * 512 + slot * 8) = val;
    }
  } else {
    const int gid  = (blk - QE_BLKS - VT_BLKS) * 4 + (t >> 6);   // 0 .. 32767
    const int lane = t & 63;
    const int mat = gid >> 14;           // 0 = k, 1 = q
    const int g = gid & 16383;
    const int kk = g & 7, pg = (g >> 3) & 63, b = g >> 9;
    const int row = pg * 16 + (lane & 15);
    const int col = kk * 32 + (lane >> 4) * 8;
    const float* src = mat ? q : k;
    ushort_t* dst = mat ? qb : kb;
    float xs[8];
#pragma unroll
    for (int e = 0; e < 8; ++e) xs[e] = 0.f;
    if (row < L) {
      const float* p = src + ((size_t)b * L + row) * H + col;
      float4a v0 = *(const float4a*)p;
      float4a v1 = *(const float4a*)(p + 4);
      xs[0] = v0.x; xs[1] = v0.y; xs[2] = v0.z; xs[3] = v0.w;
      xs[4] = v1.x; xs[5] = v1.y; xs[6] = v1.z; xs[7] = v1.w;
    }
    ushort8 h8;
#pragma unroll
    for (int e = 0; e < 8; ++e) h8[e] = f2bf(xs[e]);
    *(ushort8*)(dst + ((size_t)g << 9) + lane * 8) = h8;
  }
}

// p_lds granule addressing with bank-spread XOR (applied at ALL sites)
#define PLDS_ADDR(g_, inner_) (((size_t)(g_) << 10) + ((inner_) ^ (((g_) & 7) << 4)))

// ------------------------------------------------- fused: 64-row blocks, 16 waves, 160 KB LDS
__global__ __launch_bounds__(1024, 4) void fused_attn(const ushort_t* __restrict__ qb,
                                                      const ushort_t* __restrict__ kb,
                                                      const ushort_t* __restrict__ vt,
                                                      const float* __restrict__ qe,
                                                      float* __restrict__ attn_g,
                                                      float* __restrict__ out_g) {
  __shared__ ushort_t q_lds[32 * 512];     // 32 KB: 64 Q rows as granules; reused as sums scratch
  __shared__ ushort_t p_lds[128 * 512];    // 128 KB: granule (ni*32 + jbg), A-frag-linear + XOR

  const int bid = blockIdx.x;
  const int swz = (bid & 7) * 64 + (bid >> 3);   // XCD-chunked (512 % 8 == 0)
  const int b = swz >> 4, it = swz & 15;
  const int i0 = it * 64;
  const int tid = threadIdx.x, w = tid >> 6, lane = tid & 63;
  const int q4 = lane >> 4, ln16 = lane & 15;

  // ---- phase 0: copy this block's 32 qb granules (32 KB, layout-identical) into q_lds
  {
    const ushort_t* qsrc = qb + (((size_t)b * 64 + (i0 >> 4)) * 8) * 512;
#pragma unroll
    for (int i = 0; i < 2; ++i)
      async_copy16(qsrc + (size_t)tid * 8 + (size_t)i * 8192,
                   (char*)q_lds + tid * 16 + i * 16384);
    asm volatile("s_waitcnt vmcnt(0)" ::: "memory");
  }
  __syncthreads();

  // ---- per-lane q-row bias values (i = ni*16 + ln16, ni 0..3)
  float4a qv[4];
  float qe4[4], qe5[4];
  int gi_i[4], ci_i[4];
#pragma unroll
  for (int ni = 0; ni < 4; ++ni) {
    gi_i[ni] = i0 + ni * 16 + ln16;
    const int giC = (gi_i[ni] < L) ? gi_i[ni] : (L - 1);
    ci_i[ni] = giC / KSHOT;
    const float* qp = qe + (size_t)(b * L + giC) * 6;
    qv[ni] = *(const float4a*)qp;
    qe4[ni] = qp[4];
    qe5[ni] = qp[5];
  }

  float psum[4] = {0.f, 0.f, 0.f, 0.f};
  const ushort_t* kbB = kb + ((size_t)b * 512) * 512 + (size_t)lane * 8;

  // ---- QK^T sweeps (swapped: A = K granules, B = Q granules); wave owns 32 cols/sweep
#pragma unroll 1
  for (int s = 0; s < 2; ++s) {
    const int jb = s * 512 + w * 32;
    const int pgb = jb >> 4;               // 2 K panels (mj 0..1)
    f32x4 acc[2][4];
#pragma unroll
    for (int mj = 0; mj < 2; ++mj)
#pragma unroll
      for (int ni = 0; ni < 4; ++ni) acc[mj][ni] = (f32x4){0.f, 0.f, 0.f, 0.f};

    short8 kf[3][2];   // 2-ahead rotating prefetch of K fragments
#pragma unroll
    for (int d = 0; d < 2; ++d)
#pragma unroll
      for (int p = 0; p < 2; ++p)
        kf[d][p] = *(const short8*)(kbB + ((size_t)((pgb + p) * 8 + d) << 9));

#pragma unroll
    for (int kk = 0; kk < 8; ++kk) {
      if (kk < 6) {
#pragma unroll
        for (int p = 0; p < 2; ++p)
          kf[(kk + 2) % 3][p] =
              *(const short8*)(kbB + ((size_t)((pgb + p) * 8 + kk + 2) << 9));
      }
      short8 qf[4];
#pragma unroll
      for (int ni = 0; ni < 4; ++ni)
        qf[ni] = *(const short8*)&q_lds[(size_t)(ni * 8 + kk) * 512 + (size_t)lane * 8];
      __builtin_amdgcn_s_setprio(1);
#pragma unroll
      for (int mj = 0; mj < 2; ++mj)
#pragma unroll
        for (int ni = 0; ni < 4; ++ni)
          acc[mj][ni] = __builtin_amdgcn_mfma_f32_16x16x32_bf16(kf[kk % 3][mj], qf[ni], acc[mj][ni], 0, 0, 0);
      __builtin_amdgcn_s_setprio(0);
    }

    // epilogue: bias + exp + vectorized P-writes (b64), psum partials
    const int jbg = jb >> 5;               // col-granule 0..31
#pragma unroll
    for (int mj = 0; mj < 2; ++mj) {
      const int jbase = jb + mj * 16 + q4 * 4;
      const int boff = (ln16 | ((mj * 2 + (q4 >> 1)) << 4)) * 16 + (q4 & 1) * 8;
#pragma unroll
      for (int ni = 0; ni < 4; ++ni) {
        const int g2 = ni * 32 + jbg;
        ushort4v pw;
#pragma unroll
        for (int r = 0; r < 4; ++r) {
          const int j = jbase + r;
          const int cj = j / KSHOT;
          float bias = (ci_i[ni] == cj) ? qv[ni].y : qv[ni].z;
          if (gi_i[ni] == j) bias = qv[ni].x;
          if (j == L - 1) bias = qv[ni].w;
          if (gi_i[ni] == L - 1) bias = (j == L - 1) ? qe5[ni] : qe4[ni];
          const float e = (j < L) ? __expf((acc[mj][ni][r] + bias) * 0.0625f) : 0.f;
          psum[ni] += e;
          pw[r] = f2bf(e);
        }
        *(ushort4v*)((char*)p_lds + PLDS_ADDR(g2, boff)) = pw;
      }
    }
  }

  // ---- row sums (64 rows): reduce q4 groups, combine 16 waves via q_lds overlay
#pragma unroll
  for (int ni = 0; ni < 4; ++ni) {
    psum[ni] += __shfl_xor(psum[ni], 16, 64);
    psum[ni] += __shfl_xor(psum[ni], 32, 64);
  }
  __syncthreads();
  float* sums_f = (float*)q_lds;
  if (q4 == 0) {
#pragma unroll
    for (int ni = 0; ni < 4; ++ni)
      sums_f[w * 64 + ni * 16 + ln16] = psum[ni];
  }
  __syncthreads();
  if (tid < 64) {
    float t = 0.f;
#pragma unroll
    for (int ww = 0; ww < 16; ++ww) t += sums_f[ww * 64 + tid];
    sums_f[tid] = 1.0f / t;
  }
  __syncthreads();

  // ---- attn store phase: wave-contiguous nontemporal 1KB stores; wave w owns rows w*4..+3
  {
#pragma unroll
    for (int rr = 0; rr < 4; ++rr) {
      const int rowl = w * 4 + rr;
      const int gi = i0 + rowl;
      if (gi < L) {
        const float ivr = sums_f[rowl];
        float* arow = attn_g + ((size_t)b * L + gi) * L;
        const int gbase = (rowl >> 4) * 32;
        const int srow = rowl & 15;
#pragma unroll
        for (int c = 0; c < 4; ++c) {
          const int j4 = c * 256 + lane * 4;
          const int g = gbase + (j4 >> 5);
          const int inner = ((srow | (((j4 >> 3) & 3) << 4)) << 4) + ((j4 & 4) << 1);
          const ushort4v pb = *(const ushort4v*)((const char*)p_lds + PLDS_ADDR(g, inner));
          if (j4 + 4 <= L) {
            float4a o = {bf2f(pb[0]) * ivr, bf2f(pb[1]) * ivr,
                         bf2f(pb[2]) * ivr, bf2f(pb[3]) * ivr};
            __builtin_nontemporal_store(o, (float4a*)(arow + j4));
          } else if (j4 < L) {
#pragma unroll
            for (int e = 0; e < 4; ++e)
              if (j4 + e < L) __builtin_nontemporal_store(bf2f(pb[e]) * ivr, arow + j4 + e);
          }
        }
      }
    }
  }

  // ---- PV MFMA: wave w owns h-panel w (16 cols); vt granules 1 KB, 3-ahead; P from LDS
  f32x4 pacc[4];
#pragma unroll
  for (int m = 0; m < 4; ++m) pacc[m] = (f32x4){0.f, 0.f, 0.f, 0.f};

  const ushort_t* vg = vt + (size_t)(b * 16 + w) * 32 * 512 + (size_t)lane * 8;

  short8 vs[4];
#pragma unroll
  for (int d = 0; d < 3; ++d) vs[d] = *(const short8*)(vg + (size_t)d * 512);

#pragma unroll 4
  for (int ks = 0; ks < 32; ++ks) {
    const int sl = ks & 3;
    if (ks < 29) vs[(ks + 3) & 3] = *(const short8*)(vg + ((size_t)ks + 3) * 512);
    short8 a[4];
#pragma unroll
    for (int m = 0; m < 4; ++m)
      a[m] = *(const short8*)((const char*)p_lds + PLDS_ADDR(m * 32 + ks, lane * 16));
    __builtin_amdgcn_s_setprio(1);
#pragma unroll
    for (int m = 0; m < 4; ++m)
      pacc[m] = __builtin_amdgcn_mfma_f32_16x16x32_bf16(a[m], vs[sl], pacc[m], 0, 0, 0);
    __builtin_amdgcn_s_setprio(0);
  }

  // ---- out store; D row = m*16 + q4*4 + r, col h = w*16 + ln16
#pragma unroll
  for (int m = 0; m < 4; ++m)
#pragma unroll
    for (int r = 0; r < 4; ++r) {
      const int il = m * 16 + q4 * 4 + r;
      const int gi = i0 + il;
      if (gi < L) {
        const float iv = sums_f[il];
        __builtin_nontemporal_store(pacc[m][r] * iv,
                                    out_g + ((size_t)b * L + gi) * H + w * 16 + ln16);
      }
    }
}

// ----------------------------------------------------------------------------
extern "C" void kernel_launch(void* const* d_in, const int* in_sizes, int n_in,
                              void* d_out, int out_size, void* d_ws, size_t ws_size,
                              hipStream_t stream) {
  const float* q   = (const float*)d_in[0];
  const float* k   = (const float*)d_in[1];
  const float* v   = (const float*)d_in[2];
  const float* emb = (const float*)d_in[3];
  float* out  = (float*)d_out;
  float* attn = out + (size_t)B_DIM * L * H;

  // ws: vt 16MB | qe 1MB | kb 16MB | qb 16MB   (49 MB)
  char* wsp = (char*)d_ws;
  ushort_t* vt = (ushort_t*)wsp;
  float*    qe = (float*)(wsp + (16u << 20));
  ushort_t* kb = (ushort_t*)(wsp + (17u << 20));
  ushort_t* qb = (ushort_t*)(wsp + (33u << 20));

  prep_kernel<<<dim3(QE_BLKS + VT_BLKS + KQ_BLKS), dim3(256), 0, stream>>>(q, k, v, emb, qe, vt, kb, qb);
  fused_attn<<<dim3(512), dim3(1024), 0, stream>>>(qb, kb, vt, qe, attn, out);
}

// Round 15
// 142.272 us; speedup vs baseline: 1.4166x; 1.4166x over previous
//
#include <hip/hip_runtime.h>

#define L     1001
#define H     256
#define B_DIM 32
#define KSHOT 50

typedef float  f32x4   __attribute__((ext_vector_type(4)));
typedef short  short8  __attribute__((ext_vector_type(8)));
typedef unsigned short ushort8 __attribute__((ext_vector_type(8)));
typedef unsigned short ushort4v __attribute__((ext_vector_type(4)));
typedef float  float4a __attribute__((ext_vector_type(4), aligned(4)));
typedef unsigned short ushort_t;

__device__ __forceinline__ unsigned short f2bf(float x) {
  unsigned int u = __float_as_uint(x);
  u += 0x7FFFu + ((u >> 16) & 1u);           // RNE
  return (unsigned short)(u >> 16);
}
__device__ __forceinline__ float bf2f(unsigned short h) {
  return __uint_as_float(((unsigned int)h) << 16);
}

// ------------------------------------------------- merged prep: qe | vt | kb in one launch
#define QE_BLKS 8008
#define VT_BLKS 2048
#define KB_BLKS 4096

__global__ __launch_bounds__(256) void prep_kernel(const float* __restrict__ q,
                                                   const float* __restrict__ k,
                                                   const float* __restrict__ v,
                                                   const float* __restrict__ emb,
                                                   float* __restrict__ qe,
                                                   ushort_t* __restrict__ vt,
                                                   ushort_t* __restrict__ kb) {
  const int blk = blockIdx.x;
  const int t = threadIdx.x;
  __shared__ ushort_t tile[64][68];

  if (blk < QE_BLKS) {
    const int wid  = (blk << 2) + (t >> 6);
    const int lane = t & 63;
    if (wid >= B_DIM * L) return;
    const float4a qv = *(const float4a*)(q + (size_t)wid * H + lane * 4);
    float acc[6];
#pragma unroll
    for (int c = 0; c < 6; ++c) {
      float4a ev = *(const float4a*)(emb + c * H + lane * 4);
      acc[c] = qv.x * ev.x + qv.y * ev.y + qv.z * ev.z + qv.w * ev.w;
    }
#pragma unroll
    for (int c = 0; c < 6; ++c)
#pragma unroll
      for (int o = 32; o; o >>= 1) acc[c] += __shfl_xor(acc[c], o, 64);
    if (lane == 0) {
      float* dst = qe + (size_t)wid * 6;
      dst[0] = acc[0]; dst[1] = acc[1]; dst[2] = acc[2];
      dst[3] = acc[3]; dst[4] = acc[4]; dst[5] = acc[5];
    }
  } else if (blk < QE_BLKS + VT_BLKS) {
    const int idx = blk - QE_BLKS;
    const int jt = idx & 15, ht = (idx >> 4) & 3, b = idx >> 6;
    const int j0 = jt * 64, h0 = ht * 64;
#pragma unroll
    for (int it = 0; it < 4; ++it) {
      int j = (t >> 4) + it * 16;
      int h = (t & 15) * 4;
      int gj = j0 + j;
      float4a val = {0.f, 0.f, 0.f, 0.f};
      if (gj < L) val = *(const float4a*)(v + ((size_t)b * L + gj) * H + h0 + h);
      tile[j][h + 0] = f2bf(val.x);
      tile[j][h + 1] = f2bf(val.y);
      tile[j][h + 2] = f2bf(val.z);
      tile[j][h + 3] = f2bf(val.w);
    }
    __syncthreads();
#pragma unroll
    for (int it = 0; it < 2; ++it) {
      int h = (t >> 3) + it * 32;
      int j = (t & 7) * 8;
      ushort8 val;
#pragma unroll
      for (int e = 0; e < 8; ++e) val[e] = tile[j + e][h];
      const int hg = h0 + h, jg = j0 + j;
      const int gran = (b * 16 + (hg >> 4)) * 32 + (jg >> 5);
      const int slot = (hg & 15) | (((jg >> 3) & 3) << 4);
      *(ushort8*)(vt + (size_t)gran * 512 + slot * 8) = val;
    }
  } else {
    const int g    = (blk - QE_BLKS - VT_BLKS) * 4 + (t >> 6);
    const int lane = t & 63;
    const int kk = g & 7, pg = (g >> 3) & 63, b = g >> 9;
    const int row = pg * 16 + (lane & 15);
    const int col = kk * 32 + (lane >> 4) * 8;
    float xs[8];
#pragma unroll
    for (int e = 0; e < 8; ++e) xs[e] = 0.f;
    if (row < L) {
      const float* p = k + ((size_t)b * L + row) * H + col;
      float4a v0 = *(const float4a*)p;
      float4a v1 = *(const float4a*)(p + 4);
      xs[0] = v0.x; xs[1] = v0.y; xs[2] = v0.z; xs[3] = v0.w;
      xs[4] = v1.x; xs[5] = v1.y; xs[6] = v1.z; xs[7] = v1.w;
    }
    ushort8 h8;
#pragma unroll
    for (int e = 0; e < 8; ++e) h8[e] = f2bf(xs[e]);
    *(ushort8*)(kb + ((size_t)g << 9) + lane * 8) = h8;
  }
}

// p_lds granule addressing with bank-spread XOR (applied at ALL sites)
#define PLDS_ADDR(g_, inner_) (((size_t)(g_) << 10) + ((inner_) ^ (((g_) & 7) << 4)))

// ------------------------------------------------- fused: S^T = K.Q^T (swapped) + exp + attn + PV
// (r7/r10 champion: 118 us fused; QBLK=32, 512T, 80KB LDS, 2 blocks/CU)
__global__ __launch_bounds__(512, 4) void fused_attn(const float* __restrict__ q,
                                                     const ushort_t* __restrict__ kb,
                                                     const ushort_t* __restrict__ vt,
                                                     const float* __restrict__ qe,
                                                     float* __restrict__ attn_g,
                                                     float* __restrict__ out_g) {
  __shared__ ushort_t q_lds[16 * 512];    // 16 KB; reused as row-sum scratch
  __shared__ ushort_t p_lds[64 * 512];    // 64 KB: granule (ni*32 + jbg), A-frag-linear + XOR

  const int bid = blockIdx.x;
  const int swz = (bid & 7) * 128 + (bid >> 3);   // XCD-chunked (1024 % 8 == 0)
  const int b = swz >> 5, it = swz & 31;
  const int i0 = it * 32;
  const int tid = threadIdx.x, w = tid >> 6, lane = tid & 63;
  const int q4 = lane >> 4, ln16 = lane & 15;

  // ---- phase 0: Q f32 -> bf16 granules in q_lds
  {
    const int g  = tid >> 5;
    const int s  = (tid & 31) * 2;
    const int pg = g >> 3, kg = g & 7;
    const int colf = kg * 32 + (s >> 4) * 8;
#pragma unroll
    for (int d = 0; d < 2; ++d) {
      const int row = pg * 16 + (s & 15) + d;
      const int gi = i0 + row;
      float xs[8];
#pragma unroll
      for (int e = 0; e < 8; ++e) xs[e] = 0.f;
      if (gi < L) {
        const float* p = q + ((size_t)b * L + gi) * H + colf;
        float4a v0 = *(const float4a*)p;
        float4a v1 = *(const float4a*)(p + 4);
        xs[0] = v0.x; xs[1] = v0.y; xs[2] = v0.z; xs[3] = v0.w;
        xs[4] = v1.x; xs[5] = v1.y; xs[6] = v1.z; xs[7] = v1.w;
      }
      ushort8 h8;
#pragma unroll
      for (int e = 0; e < 8; ++e) h8[e] = f2bf(xs[e]);
      *(ushort8*)&q_lds[(size_t)g * 512 + (size_t)(s + d) * 8] = h8;
    }
  }
  __syncthreads();

  // ---- per-lane q-row bias values (i = ni*16 + ln16)
  float4a qv[2];
  float qe4[2], qe5[2];
  int gi_i[2], ci_i[2];
#pragma unroll
  for (int ni = 0; ni < 2; ++ni) {
    gi_i[ni] = i0 + ni * 16 + ln16;
    const int giC = (gi_i[ni] < L) ? gi_i[ni] : (L - 1);
    ci_i[ni] = giC / KSHOT;
    const float* qp = qe + (size_t)(b * L + giC) * 6;
    qv[ni] = *(const float4a*)qp;
    qe4[ni] = qp[4];
    qe5[ni] = qp[5];
  }

  float psum[2] = {0.f, 0.f};
  const ushort_t* kbB = kb + ((size_t)b * 512) * 512 + (size_t)lane * 8;

  // ---- QK^T sweeps (swapped: A = K granules, B = Q granules)
#pragma unroll 1
  for (int s = 0; s < 2; ++s) {
    const int jb = s * 512 + w * 64;
    const int pgb = jb >> 4;
    f32x4 acc[4][2];
#pragma unroll
    for (int mj = 0; mj < 4; ++mj)
#pragma unroll
      for (int ni = 0; ni < 2; ++ni) acc[mj][ni] = (f32x4){0.f, 0.f, 0.f, 0.f};

    short8 kf[3][4];   // 2-ahead rotating prefetch of K fragments
#pragma unroll
    for (int d = 0; d < 2; ++d)
#pragma unroll
      for (int p = 0; p < 4; ++p)
        kf[d][p] = *(const short8*)(kbB + ((size_t)((pgb + p) * 8 + d) << 9));

#pragma unroll
    for (int kk = 0; kk < 8; ++kk) {
      if (kk < 6) {
#pragma unroll
        for (int p = 0; p < 4; ++p)
          kf[(kk + 2) % 3][p] =
              *(const short8*)(kbB + ((size_t)((pgb + p) * 8 + kk + 2) << 9));
      }
      short8 qf0 = *(const short8*)&q_lds[(size_t)kk * 512 + (size_t)lane * 8];
      short8 qf1 = *(const short8*)&q_lds[(size_t)(8 + kk) * 512 + (size_t)lane * 8];
      __builtin_amdgcn_s_setprio(1);
#pragma unroll
      for (int mj = 0; mj < 4; ++mj) {
        acc[mj][0] = __builtin_amdgcn_mfma_f32_16x16x32_bf16(kf[kk % 3][mj], qf0, acc[mj][0], 0, 0, 0);
        acc[mj][1] = __builtin_amdgcn_mfma_f32_16x16x32_bf16(kf[kk % 3][mj], qf1, acc[mj][1], 0, 0, 0);
      }
      __builtin_amdgcn_s_setprio(0);
    }

    // epilogue: bias + exp + vectorized P-writes (b64), psum partials
#pragma unroll
    for (int mj = 0; mj < 4; ++mj) {
      const int jbase = jb + mj * 16 + q4 * 4;
      const int jbg = (jb >> 5) + (mj >> 1);
      const int boff = (ln16 | (((mj & 1) * 2 + (q4 >> 1)) << 4)) * 16 + (q4 & 1) * 8;
#pragma unroll
      for (int ni = 0; ni < 2; ++ni) {
        const int g2 = ni * 32 + jbg;
        ushort4v pw;
#pragma unroll
        for (int r = 0; r < 4; ++r) {
          const int j = jbase + r;
          const int cj = j / KSHOT;
          float bias = (ci_i[ni] == cj) ? qv[ni].y : qv[ni].z;
          if (gi_i[ni] == j) bias = qv[ni].x;
          if (j == L - 1) bias = qv[ni].w;
          if (gi_i[ni] == L - 1) bias = (j == L - 1) ? qe5[ni] : qe4[ni];
          const float e = (j < L) ? __expf((acc[mj][ni][r] + bias) * 0.0625f) : 0.f;
          psum[ni] += e;
          pw[r] = f2bf(e);
        }
        *(ushort4v*)((char*)p_lds + PLDS_ADDR(g2, boff)) = pw;
      }
    }
  }

  // ---- row sums
#pragma unroll
  for (int ni = 0; ni < 2; ++ni) {
    psum[ni] += __shfl_xor(psum[ni], 16, 64);
    psum[ni] += __shfl_xor(psum[ni], 32, 64);
  }
  __syncthreads();
  float* sums_f = (float*)q_lds;
  if (q4 == 0) {
    sums_f[w * 32 + ln16] = psum[0];
    sums_f[w * 32 + 16 + ln16] = psum[1];
  }
  __syncthreads();
  if (tid < 32) {
    float t = 0.f;
#pragma unroll
    for (int ww = 0; ww < 8; ++ww) t += sums_f[ww * 32 + tid];
    sums_f[tid] = 1.0f / t;
  }
  __syncthreads();

  // ---- attn store phase: wave-contiguous nontemporal 1KB stores; wave w owns rows w*4..+3
  {
#pragma unroll
    for (int rr = 0; rr < 4; ++rr) {
      const int rowl = w * 4 + rr;
      const int gi = i0 + rowl;
      if (gi < L) {
        const float ivr = sums_f[rowl];
        float* arow = attn_g + ((size_t)b * L + gi) * L;
        const int gbase = (rowl >> 4) * 32;
        const int srow = rowl & 15;
#pragma unroll
        for (int c = 0; c < 4; ++c) {
          const int j4 = c * 256 + lane * 4;
          const int g = gbase + (j4 >> 5);
          const int inner = ((srow | (((j4 >> 3) & 3) << 4)) << 4) + ((j4 & 4) << 1);
          const ushort4v pb = *(const ushort4v*)((const char*)p_lds + PLDS_ADDR(g, inner));
          if (j4 + 4 <= L) {
            float4a o = {bf2f(pb[0]) * ivr, bf2f(pb[1]) * ivr,
                         bf2f(pb[2]) * ivr, bf2f(pb[3]) * ivr};
            __builtin_nontemporal_store(o, (float4a*)(arow + j4));
          } else if (j4 < L) {
#pragma unroll
            for (int e = 0; e < 4; ++e)
              if (j4 + e < L) __builtin_nontemporal_store(bf2f(pb[e]) * ivr, arow + j4 + e);
          }
        }
      }
    }
  }

  // ---- PV MFMA: vt granules (contiguous 1 KB loads), 3-ahead prefetch; P from LDS
  f32x4 pacc[2][2];
#pragma unroll
  for (int m = 0; m < 2; ++m)
#pragma unroll
    for (int n = 0; n < 2; ++n) pacc[m][n] = (f32x4){0.f, 0.f, 0.f, 0.f};

  const ushort_t* vg = vt + (size_t)(b * 16 + w * 2) * 32 * 512 + (size_t)lane * 8;

  short8 vs[4][2];
#pragma unroll
  for (int d = 0; d < 3; ++d)
#pragma unroll
    for (int n = 0; n < 2; ++n)
      vs[d][n] = *(const short8*)(vg + ((size_t)n * 32 + d) * 512);

#pragma unroll 4
  for (int ks = 0; ks < 32; ++ks) {
    const int sl = ks & 3;
    if (ks < 29) {
#pragma unroll
      for (int n = 0; n < 2; ++n)
        vs[(ks + 3) & 3][n] = *(const short8*)(vg + ((size_t)n * 32 + ks + 3) * 512);
    }
    short8 a[2];
#pragma unroll
    for (int m = 0; m < 2; ++m)
      a[m] = *(const short8*)((const char*)p_lds + PLDS_ADDR(m * 32 + ks, lane * 16));
    __builtin_amdgcn_s_setprio(1);
#pragma unroll
    for (int m = 0; m < 2; ++m)
#pragma unroll
      for (int n = 0; n < 2; ++n)
        pacc[m][n] = __builtin_amdgcn_mfma_f32_16x16x32_bf16(a[m], vs[sl][n], pacc[m][n], 0, 0, 0);
    __builtin_amdgcn_s_setprio(0);
  }

  // ---- out store; D row = m*16 + q4*4 + r, col h = w*32 + n*16 + ln16
#pragma unroll
  for (int m = 0; m < 2; ++m)
#pragma unroll
    for (int r = 0; r < 4; ++r) {
      const int il = m * 16 + q4 * 4 + r;
      const int gi = i0 + il;
      if (gi < L) {
        const float iv = sums_f[il];
#pragma unroll
        for (int n = 0; n < 2; ++n)
          __builtin_nontemporal_store(pacc[m][n][r] * iv,
                                      out_g + ((size_t)b * L + gi) * H + w * 32 + n * 16 + ln16);
      }
    }
}

// ----------------------------------------------------------------------------
extern "C" void kernel_launch(void* const* d_in, const int* in_sizes, int n_in,
                              void* d_out, int out_size, void* d_ws, size_t ws_size,
                              hipStream_t stream) {
  const float* q   = (const float*)d_in[0];
  const float* k   = (const float*)d_in[1];
  const float* v   = (const float*)d_in[2];
  const float* emb = (const float*)d_in[3];
  float* out  = (float*)d_out;
  float* attn = out + (size_t)B_DIM * L * H;

  // ws: vt 16MB | qe 1MB | kb 16MB   (33 MB)
  char* wsp = (char*)d_ws;
  ushort_t* vt = (ushort_t*)wsp;
  float*    qe = (float*)(wsp + (16u << 20));
  ushort_t* kb = (ushort_t*)(wsp + (17u << 20));

  prep_kernel<<<dim3(QE_BLKS + VT_BLKS + KB_BLKS), dim3(256), 0, stream>>>(q, k, v, emb, qe, vt, kb);
  fused_attn<<<dim3(1024), dim3(512), 0, stream>>>(q, kb, vt, qe, attn, out);
}